// Round 11
// baseline (150.853 us; speedup 1.0000x reference)
//
#include <hip/hip_runtime.h>
#include <math.h>

#define B_      16
#define H_      32
#define KVH_    8
#define G_      4
#define D_      128
#define BS_     16
#define L_      4096
#define MAXB_   256
#define T_      4096
#define NPART_  32
#define PART_   128
#define GRID_   (B_ * KVH_ * NPART_)   // 4096
#define SCALE_  0.08838834764831843f

__device__ __forceinline__ int seq_len_of(int ctx) {
  return (ctx >= L_) ? (L_ - BS_ + (ctx & (BS_ - 1)) + 1) : (ctx + 1);
}

// Partial attention per (b, kvh, 128-token partition). 256 threads = 4 waves;
// 16 lanes per position (4 positions/wave/iter, stride 16). Lane dg holds dims
// [4dg..4dg+3] and [64+4dg..64+4dg+3] (4 RoPE pairs, lane-local). Cos/sin
// initialized ONCE per lane with the exact table math (f64 pow -> f32-rounded
// angle -> f64 sincos) and advanced in-register by angle-addition. Depth-1
// A/B register prefetch; block-table slice in LDS.
//
// XCD swizzle: the 8 kvh-siblings of one (b,part) read the SAME token records
// ([blk][slot][kvh][D] layout) -> co-locate them on one XCD (assume XCD =
// bid%8, m157-consistent) so the XCD's L2 fetches each record once, not 8x.
// Sibling-groups round-robin across XCDs for balance.

#define LOADK(P, tt)                                                        \
  {                                                                         \
    int blk_  = sblk[((tt) - t0) >> 4];                                     \
    int base_ = ((blk_ * BS_ + ((tt) & (BS_ - 1))) * KVH_ + kvh) * D_;      \
    const float4* kc4_ = (const float4*)(kc + base_);                       \
    const float4* vc4_ = (const float4*)(vc + base_);                       \
    P##ka = kc4_[dg];      P##kb = kc4_[16 + dg];                           \
    P##va = vc4_[dg];      P##vb = vc4_[16 + dg];                           \
  }

#define COMPUTE(P, tt)                                                      \
  {                                                                         \
    float kr1[4], kr2[4];                                                   \
    kr1[0] = P##ka.x * cc0.x - P##kb.x * cc0.y;                             \
    kr2[0] = P##kb.x * cc0.x + P##ka.x * cc0.y;                             \
    kr1[1] = P##ka.y * cc0.z - P##kb.y * cc0.w;                             \
    kr2[1] = P##kb.y * cc0.z + P##ka.y * cc0.w;                             \
    kr1[2] = P##ka.z * cc1.x - P##kb.z * cc1.y;                             \
    kr2[2] = P##kb.z * cc1.x + P##ka.z * cc1.y;                             \
    kr1[3] = P##ka.w * cc1.z - P##kb.w * cc1.w;                             \
    kr2[3] = P##kb.w * cc1.z + P##ka.w * cc1.w;                             \
    bool valid_ = ((tt) != posq);                                           \
    float s[G_];                                                            \
    _Pragma("unroll")                                                       \
    for (int g = 0; g < G_; ++g) {                                          \
      s[g] = kr1[0] * q1[g][0] + kr2[0] * q2[g][0]                          \
           + kr1[1] * q1[g][1] + kr2[1] * q2[g][1]                          \
           + kr1[2] * q1[g][2] + kr2[2] * q2[g][2]                          \
           + kr1[3] * q1[g][3] + kr2[3] * q2[g][3];                         \
    }                                                                       \
    _Pragma("unroll")                                                       \
    for (int off = 1; off <= 8; off <<= 1) {                                \
      _Pragma("unroll")                                                     \
      for (int g = 0; g < G_; ++g) s[g] += __shfl_xor(s[g], off);           \
    }                                                                       \
    _Pragma("unroll")                                                       \
    for (int g = 0; g < G_; ++g) {                                          \
      float sv = valid_ ? s[g] : -1e30f;                                    \
      if (sv > m[g]) {               /* group-uniform, rare after warmup */ \
        float corr = __expf(m[g] - sv);                                     \
        l[g] = l[g] * corr + 1.0f;                                          \
        acc[g][0] = acc[g][0] * corr + P##va.x;                             \
        acc[g][1] = acc[g][1] * corr + P##va.y;                             \
        acc[g][2] = acc[g][2] * corr + P##va.z;                             \
        acc[g][3] = acc[g][3] * corr + P##va.w;                             \
        acc[g][4] = acc[g][4] * corr + P##vb.x;                             \
        acc[g][5] = acc[g][5] * corr + P##vb.y;                             \
        acc[g][6] = acc[g][6] * corr + P##vb.z;                             \
        acc[g][7] = acc[g][7] * corr + P##vb.w;                             \
        m[g] = sv;                                                          \
      } else {                                                              \
        float p = __expf(sv - m[g]);                                        \
        p = valid_ ? p : 0.0f;                                              \
        l[g] += p;                                                          \
        acc[g][0] += p * P##va.x;                                           \
        acc[g][1] += p * P##va.y;                                           \
        acc[g][2] += p * P##va.z;                                           \
        acc[g][3] += p * P##va.w;                                           \
        acc[g][4] += p * P##vb.x;                                           \
        acc[g][5] += p * P##vb.y;                                           \
        acc[g][6] += p * P##vb.z;                                           \
        acc[g][7] += p * P##vb.w;                                           \
      }                                                                     \
    }                                                                       \
    { /* advance cos/sin by 16*theta (angle addition) */                    \
      float nc_;                                                            \
      nc_ = cc0.x * r0.x - cc0.y * r0.y;                                    \
      cc0.y = cc0.y * r0.x + cc0.x * r0.y; cc0.x = nc_;                     \
      nc_ = cc0.z * r0.z - cc0.w * r0.w;                                    \
      cc0.w = cc0.w * r0.z + cc0.z * r0.w; cc0.z = nc_;                     \
      nc_ = cc1.x * r1.x - cc1.y * r1.y;                                    \
      cc1.y = cc1.y * r1.x + cc1.x * r1.y; cc1.x = nc_;                     \
      nc_ = cc1.z * r1.z - cc1.w * r1.w;                                    \
      cc1.w = cc1.w * r1.z + cc1.z * r1.w; cc1.z = nc_;                     \
    }                                                                       \
  }

__global__ __launch_bounds__(256) void attn_partial_kernel(
    const float* __restrict__ q, const float* __restrict__ knew,
    const float* __restrict__ vnew, const float* __restrict__ kc,
    const float* __restrict__ vc, const int* __restrict__ btab,
    const int* __restrict__ ctxl,
    float* __restrict__ opart, float2* __restrict__ ml) {
  // sibling-co-locating XCD swizzle (bijective on [0,4096)):
  // xcd x hosts bids {p : p%8==x}; give it sibling-groups g with g%8==x,
  // members (kvh) packed onto the same xcd.
  int p    = blockIdx.x;
  int x    = p & 7;
  int i    = p >> 3;
  int grp  = x + (i & ~7);               // (b,part) group, g%8 == x
  int kvh  = i & 7;
  int part = grp & (NPART_ - 1);
  int b    = grp >> 5;                   // NPART_ == 32
  int bid  = (b * KVH_ + kvh) * NPART_ + part;   // output index

  int seq = seq_len_of(ctxl[b]);
  int t0 = part * PART_;
  if (t0 >= seq) return;                 // uniform per block: safe early exit
  int t1 = min(t0 + PART_, seq);
  int posq = seq - 1;

  int lane = threadIdx.x & 63;
  int wave = threadIdx.x >> 6;
  int tsub = lane >> 4;
  int dg   = lane & 15;

  // block table slice for this partition -> LDS (index == (t - t0) >> 4)
  __shared__ int sblk[PART_ / BS_];
  if (threadIdx.x < PART_ / BS_)
    sblk[threadIdx.x] = btab[b * MAXB_ + (t0 >> 4) + threadIdx.x];
  __syncthreads();

  // per-lane cos/sin (pairs 4dg..4dg+3): at tstart (cc), rotation by 16
  // steps (r), at posq (cq). Exact table math: f64 pow -> f32-rounded
  // angle -> f64 sincos. Computed once per lane.
  int tstart = t0 + 4 * wave + tsub;
  float4 cc0, cc1, r0, r1, cq0, cq1;
  {
    float ft = (float)tstart, fq = (float)posq;
    float cs[3][8];
#pragma unroll
    for (int j = 0; j < 4; ++j) {
      double invd = pow(10000.0, -(double)(8 * dg + 2 * j) / 128.0);
      float invf = (float)invd;
      float angs[3] = {ft * invf, 16.0f * invf, fq * invf};
#pragma unroll
      for (int u = 0; u < 3; ++u) {
        double sn, csn;
        sincos((double)angs[u], &sn, &csn);
        cs[u][2 * j]     = (float)csn;
        cs[u][2 * j + 1] = (float)sn;
      }
    }
    cc0 = make_float4(cs[0][0], cs[0][1], cs[0][2], cs[0][3]);
    cc1 = make_float4(cs[0][4], cs[0][5], cs[0][6], cs[0][7]);
    r0  = make_float4(cs[1][0], cs[1][1], cs[1][2], cs[1][3]);
    r1  = make_float4(cs[1][4], cs[1][5], cs[1][6], cs[1][7]);
    cq0 = make_float4(cs[2][0], cs[2][1], cs[2][2], cs[2][3]);
    cq1 = make_float4(cs[2][4], cs[2][5], cs[2][6], cs[2][7]);
  }

  // roped + scaled q fragments for the 4 heads of this kv group
  float q1[G_][4], q2[G_][4];
#pragma unroll
  for (int g = 0; g < G_; ++g) {
    const float* qp = q + b * (H_ * D_) + (kvh * G_ + g) * D_;
    float4 a  = *(const float4*)(qp + 4 * dg);
    float4 bq = *(const float4*)(qp + 64 + 4 * dg);
    q1[g][0] = (a.x * cq0.x - bq.x * cq0.y) * SCALE_;
    q2[g][0] = (bq.x * cq0.x + a.x * cq0.y) * SCALE_;
    q1[g][1] = (a.y * cq0.z - bq.y * cq0.w) * SCALE_;
    q2[g][1] = (bq.y * cq0.z + a.y * cq0.w) * SCALE_;
    q1[g][2] = (a.z * cq1.x - bq.z * cq1.y) * SCALE_;
    q2[g][2] = (bq.z * cq1.x + a.z * cq1.y) * SCALE_;
    q1[g][3] = (a.w * cq1.z - bq.w * cq1.w) * SCALE_;
    q2[g][3] = (bq.w * cq1.z + a.w * cq1.w) * SCALE_;
  }

  float m[G_], l[G_], acc[G_][8];
#pragma unroll
  for (int g = 0; g < G_; ++g) {
    m[g] = -1e30f; l[g] = 0.f;
#pragma unroll
    for (int j = 0; j < 8; ++j) acc[g][j] = 0.f;
  }

  // depth-1 software pipeline (named A/B buffers)
  {
    float4 Aka, Akb, Ava, Avb;
    float4 Bka, Bkb, Bva, Bvb;
    int t = tstart;                      // group-uniform; shuffles in-group
    if (t < t1) {
      LOADK(A, t);
      while (1) {
        int t2 = t + 16;
        if (t2 < t1) LOADK(B, t2);
        COMPUTE(A, t);
        t = t2;
        if (t >= t1) break;
        t2 = t + 16;
        if (t2 < t1) LOADK(A, t2);
        COMPUTE(B, t);
        t = t2;
        if (t >= t1) break;
      }
    }
  }

  // current-token contribution: ONLY WAVE 0, lanes 0-15 (exactly once)
  if (threadIdx.x < 16 && posq >= t0 && posq < t1) {
    const float* kp = knew + (b * KVH_ + kvh) * D_;
    float4 xa = *(const float4*)(kp + 4 * dg);
    float4 xb = *(const float4*)(kp + 64 + 4 * dg);
    float kr1[4], kr2[4];
    kr1[0] = xa.x * cq0.x - xb.x * cq0.y;  kr2[0] = xb.x * cq0.x + xa.x * cq0.y;
    kr1[1] = xa.y * cq0.z - xb.y * cq0.w;  kr2[1] = xb.y * cq0.z + xa.y * cq0.w;
    kr1[2] = xa.z * cq1.x - xb.z * cq1.y;  kr2[2] = xb.z * cq1.x + xa.z * cq1.y;
    kr1[3] = xa.w * cq1.z - xb.w * cq1.w;  kr2[3] = xb.w * cq1.z + xa.w * cq1.w;
    const float* vp = vnew + (b * KVH_ + kvh) * D_;
    float4 va_ = *(const float4*)(vp + 4 * dg);
    float4 vb_ = *(const float4*)(vp + 64 + 4 * dg);
    float s[G_];
#pragma unroll
    for (int g = 0; g < G_; ++g) {
      s[g] = kr1[0] * q1[g][0] + kr2[0] * q2[g][0]
           + kr1[1] * q1[g][1] + kr2[1] * q2[g][1]
           + kr1[2] * q1[g][2] + kr2[2] * q2[g][2]
           + kr1[3] * q1[g][3] + kr2[3] * q2[g][3];
    }
#pragma unroll
    for (int off = 1; off <= 8; off <<= 1) {
#pragma unroll
      for (int g = 0; g < G_; ++g) s[g] += __shfl_xor(s[g], off);
    }
#pragma unroll
    for (int g = 0; g < G_; ++g) {
      float sv   = s[g];
      float mn   = fmaxf(m[g], sv);
      float corr = __expf(m[g] - mn);
      float p    = __expf(sv - mn);
      m[g] = mn;
      l[g] = l[g] * corr + p;
      acc[g][0] = acc[g][0] * corr + p * va_.x;
      acc[g][1] = acc[g][1] * corr + p * va_.y;
      acc[g][2] = acc[g][2] * corr + p * va_.z;
      acc[g][3] = acc[g][3] * corr + p * va_.w;
      acc[g][4] = acc[g][4] * corr + p * vb_.x;
      acc[g][5] = acc[g][5] * corr + p * vb_.y;
      acc[g][6] = acc[g][6] * corr + p * vb_.z;
      acc[g][7] = acc[g][7] * corr + p * vb_.w;
    }
  }

  // online-softmax state merge across lane groups (xor 16, 32), then waves via LDS
  auto merge_off = [&](int off) {
#pragma unroll
    for (int g = 0; g < G_; ++g) {
      float mo = __shfl_xor(m[g], off);
      float lo = __shfl_xor(l[g], off);
      float M  = fmaxf(m[g], mo);
      float fa = __expf(m[g] - M);
      float fb = __expf(mo - M);
      l[g] = l[g] * fa + lo * fb;
      m[g] = M;
#pragma unroll
      for (int j = 0; j < 8; ++j) {
        float ao = __shfl_xor(acc[g][j], off);
        acc[g][j] = acc[g][j] * fa + ao * fb;
      }
    }
  };
  merge_off(16);
  merge_off(32);

  __shared__ float  lds_acc[4][G_][D_];
  __shared__ float2 lds_ml[4][G_];
  if (lane < 16) {
#pragma unroll
    for (int g = 0; g < G_; ++g) {
#pragma unroll
      for (int j = 0; j < 8; ++j) {
        int dim = (j < 4) ? (4 * dg + j) : (64 + 4 * dg + (j - 4));
        lds_acc[wave][g][dim] = acc[g][j];
      }
      if (lane == 0) lds_ml[wave][g] = make_float2(m[g], l[g]);
    }
  }
  __syncthreads();
  if (wave == 0) {
    int w = tsub;
#pragma unroll
    for (int g = 0; g < G_; ++g) {
      float2 t2 = lds_ml[w][g];
      m[g] = t2.x; l[g] = t2.y;
#pragma unroll
      for (int j = 0; j < 8; ++j) {
        int dim = (j < 4) ? (4 * dg + j) : (64 + 4 * dg + (j - 4));
        acc[g][j] = lds_acc[w][g][dim];
      }
    }
    merge_off(16);
    merge_off(32);
    if (lane < 16) {
#pragma unroll
      for (int g = 0; g < G_; ++g) {
        float* op = opart + (size_t)(bid * G_ + g) * D_;
#pragma unroll
        for (int j = 0; j < 8; ++j) {
          int dim = (j < 4) ? (4 * dg + j) : (64 + 4 * dg + (j - 4));
          op[dim] = acc[g][j];
        }
        if (lane == 0) ml[bid * G_ + g] = make_float2(m[g], l[g]);
      }
    }
  }
}

// Merge partitions, normalize, write output.
__global__ void attn_reduce_kernel(const float* __restrict__ opart,
                                   const float2* __restrict__ ml,
                                   const int* __restrict__ ctxl,
                                   float* __restrict__ out) {
  int bh = blockIdx.x;              // 0..B*H-1
  int b = bh >> 5, h = bh & 31;
  int kvh = h >> 2, g = h & 3;
  int d = threadIdx.x;              // 0..127
  int seq = seq_len_of(ctxl[b]);
  int nlive = (seq + PART_ - 1) / PART_;
  int base = (b * KVH_ + kvh) * NPART_;

  float M = -1e30f;
  for (int p = 0; p < nlive; ++p) M = fmaxf(M, ml[(base + p) * G_ + g].x);
  float L = 0.f, O = 0.f;
  for (int p = 0; p < nlive; ++p) {
    float2 mlv = ml[(base + p) * G_ + g];
    float f = __expf(mlv.x - M);
    L += mlv.y * f;
    O += opart[(size_t)((base + p) * G_ + g) * D_ + d] * f;
  }
  out[b * (H_ * D_) + h * D_ + d] = O / L;
}

extern "C" void kernel_launch(void* const* d_in, const int* in_sizes, int n_in,
                              void* d_out, int out_size, void* d_ws, size_t ws_size,
                              hipStream_t stream) {
  const float* q    = (const float*)d_in[0];
  const float* k    = (const float*)d_in[1];
  const float* v    = (const float*)d_in[2];
  const float* kc   = (const float*)d_in[3];
  const float* vc   = (const float*)d_in[4];
  const int*   btab = (const int*)d_in[5];
  const int*   ctxl = (const int*)d_in[6];
  float* out = (float*)d_out;

  float*  opart = (float*)d_ws;                                  // 8.4 MB
  float2* ml    = (float2*)(opart + (size_t)B_ * KVH_ * NPART_ * G_ * D_); // 128 KB

  attn_partial_kernel<<<GRID_, 256, 0, stream>>>(
      q, k, v, kc, vc, btab, ctxl, opart, ml);
  attn_reduce_kernel<<<B_ * H_, D_, 0, stream>>>(opart, ml, ctxl, out);
}